// Round 3
// baseline (25.335 us; speedup 1.0000x reference)
//
#include <hip/hip_runtime.h>

// Problem constants (match reference)
constexpr int Bc = 128;
constexpr int Nc = 256;
constexpr int Hc = 272;
constexpr int Wc = 152;
constexpr int RMAXc = 8;
constexpr int HWc = Hc * Wc;

constexpr int SPLIT = 4;          // row chunks per batch image
constexpr int CH    = Hc / SPLIT; // 68 rows per chunk
constexpr int W4    = Wc / 4;     // 38 float4 per row

// One block per (batch, row-chunk). Phases:
//  1. zero 68x152 LDS slab
//  2. one object per LANE: gather + param compute (256 gathers in flight)
//  3. wave-per-object scatter into LDS via atomicMax(int) — values >= 0 so
//     int ordering == float ordering; window rows clipped to this chunk
//  4. coalesced float4 stream LDS -> global (every output byte written once)
__global__ __launch_bounds__(256) void fused_gaussian_kernel(
    const float* __restrict__ flow,   // [B,2,H,W]
    const float* __restrict__ wh,     // [B,N,4]
    const int*   __restrict__ mask,   // [B,N]
    const int*   __restrict__ index,  // [B,N]
    float*       __restrict__ hm)     // [B,H,W]
{
    __shared__ int   s_hm[CH * Wc];   // 41344 B
    __shared__ int   s_xi[Nc], s_yi[Nc], s_ri[Nc];
    __shared__ float s_dn[Nc];

    const int tid   = threadIdx.x;
    const int b     = blockIdx.x >> 2;
    const int chunk = blockIdx.x & 3;
    const int rowLo = chunk * CH;
    const int rowHi = rowLo + CH;

    // Phase 1: zero the LDS slab
    for (int i = tid; i < CH * Wc; i += 256) s_hm[i] = 0;

    // Phase 2: per-lane object param compute (obj = b*256 + tid)
    {
        const int obj = b * Nc + tid;
        int   ri = -1, xi = 0, yi = 0;
        float dn = 1.0f;
        if (mask[obj] != 0) {
            const int   idx = index[obj];
            const float x  = flow[(b * 2 + 0) * HWc + idx];
            const float y  = flow[(b * 2 + 1) * HWc + idx];
            const float4 whv = *reinterpret_cast<const float4*>(wh + obj * 4);
            const float w = whv.x + whv.z;
            const float h = whv.y + whv.w;
            if (h > 0.0f && w > 0.0f && x > 0.0f && y > 0.0f &&
                x < 152.0f && y < 272.0f) {
                // gaussian_radius(ceil(h), ceil(w)) — f32 op order as reference
                const float height = ceilf(h);
                const float width  = ceilf(w);

                const float b1  = height + width;
                const float c1  = width * height * 0.3f / 1.7f;
                const float sq1 = sqrtf(b1 * b1 - 4.0f * c1);
                const float r1  = (b1 + sq1) * 0.5f;

                const float b2  = 2.0f * (height + width);
                const float c2  = 0.3f * width * height;
                const float sq2 = sqrtf(b2 * b2 - 16.0f * c2);
                const float r2  = (b2 + sq2) * 0.5f;

                const float b3  = -1.4f * (height + width);
                const float c3  = -0.3f * width * height;
                const float sq3 = sqrtf(b3 * b3 - 11.2f * c3);
                const float r3  = (b3 + sq3) * 0.5f;

                float radius = fminf(fminf(r1, r2), r3);
                radius = fmaxf(radius, 0.0f);
                if (radius >= 0.0f) {            // NaN guard
                    const float rf = floorf(radius);
                    ri = (int)rf;
                    if (ri > RMAXc) ri = RMAXc;
                    const float sigma = (2.0f * rf + 1.0f) / 6.0f;
                    dn = 2.0f * sigma * sigma;
                    xi = (int)floorf(x);
                    yi = (int)floorf(y);
                }
            }
        }
        s_xi[tid] = xi; s_yi[tid] = yi; s_ri[tid] = ri; s_dn[tid] = dn;
    }
    __syncthreads();

    // Phase 3: wave-per-object scatter (rows clipped to [rowLo, rowHi))
    const int wave = tid >> 6;
    const int lane = tid & 63;
    for (int o = wave; o < Nc; o += 4) {
        const int ri = s_ri[o];
        if (ri < 0) continue;
        const int   xi = s_xi[o];
        const int   yi = s_yi[o];
        const float dn = s_dn[o];

        int dyLo = -ri, dyHi = ri;
        if (yi + dyLo < rowLo)     dyLo = rowLo - yi;
        if (yi + dyHi > rowHi - 1) dyHi = rowHi - 1 - yi;
        if (dyLo > dyHi) continue;                 // window misses this chunk

        const int dw    = 2 * ri + 1;
        const int ncell = (dyHi - dyLo + 1) * dw;
        for (int c = lane; c < ncell; c += 64) {
            const int dy = dyLo + c / dw;
            const int dx = c % dw - ri;
            const int xx = xi + dx;
            if (xx < 0 || xx >= Wc) continue;
            const float dist2 = (float)(dx * dx + dy * dy);
            const float g = expf(-dist2 / dn);
            if (g < 2e-15f) continue;              // max(0) no-op on zeroed slab
            atomicMax(&s_hm[(yi + dy - rowLo) * Wc + xx], __float_as_int(g));
        }
    }
    __syncthreads();

    // Phase 4: coalesced float4 stream-out of the slab
    {
        float4* out4 = reinterpret_cast<float4*>(hm + (size_t)(b * Hc + rowLo) * Wc);
        const float4* l4 = reinterpret_cast<const float4*>(s_hm);
        for (int i = tid; i < CH * W4; i += 256) out4[i] = l4[i];
    }
}

extern "C" void kernel_launch(void* const* d_in, const int* in_sizes, int n_in,
                              void* d_out, int out_size, void* d_ws, size_t ws_size,
                              hipStream_t stream) {
    const float* flow  = (const float*)d_in[0];  // [B,2,H,W] f32
    const float* wh    = (const float*)d_in[1];  // [B,N,4]   f32
    const int*   mask  = (const int*)d_in[2];    // [B,N]     i32
    const int*   index = (const int*)d_in[3];    // [B,N]     i32
    float* hm = (float*)d_out;                   // [B,1,H,W] f32

    // 128 batches x 4 row-chunks; every output byte is written by exactly
    // one block (no memset, no global atomics needed).
    fused_gaussian_kernel<<<Bc * SPLIT, 256, 0, stream>>>(flow, wh, mask, index, hm);
}

// Round 4
// 22.628 us; speedup vs baseline: 1.1196x; 1.1196x over previous
//
#include <hip/hip_runtime.h>

// Problem constants (match reference)
constexpr int Bc = 128;
constexpr int Nc = 256;
constexpr int Hc = 272;
constexpr int Wc = 152;
constexpr int RMAXc = 8;
constexpr int HWc = Hc * Wc;

constexpr int SPLIT = 8;          // row chunks per batch image
constexpr int CH    = Hc / SPLIT; // 34 rows per chunk
constexpr int W4    = Wc / 4;     // 38 float4 per row

// One block per (batch, row-chunk); every output byte owned by exactly one
// block (no memset, no global atomics). Phases:
//  1. issue all global loads (one OBJECT per THREAD -> 256 independent
//     gathers in flight) while zeroing the LDS slab
//  2. per-thread param compute; compact objects intersecting this chunk
//     into an LDS list (atomicAdd, ~20 entries typical)
//  3. wave-per-listed-object scatter into the slab via LDS atomicMax on
//     int-punned floats (g >= 0 so int order == float order)
//  4. coalesced float4 stream-out (each byte written exactly once)
__global__ __launch_bounds__(256) void fused_gaussian_kernel(
    const float* __restrict__ flow,   // [B,2,H,W]
    const float* __restrict__ wh,     // [B,N,4]
    const int*   __restrict__ mask,   // [B,N]
    const int*   __restrict__ index,  // [B,N]
    float*       __restrict__ hm)     // [B,H,W]
{
    __shared__ int   s_hm[CH * Wc];   // 20672 B
    __shared__ int   s_xi[Nc], s_yi[Nc], s_ri[Nc];
    __shared__ float s_dn[Nc];
    __shared__ int   s_n;

    const int tid   = threadIdx.x;
    const int b     = blockIdx.x >> 3;
    const int chunk = blockIdx.x & 7;
    const int rowLo = chunk * CH;
    const int rowHi = rowLo + CH;

    if (tid == 0) s_n = 0;

    // ---- Phase 1+2a: issue ALL loads up-front (independent; only flow
    // depends on index), then zero the slab while they are in flight.
    const int obj = b * Nc + tid;
    const int   mk  = mask[obj];
    const int   idx = index[obj];
    const float4 whv = *reinterpret_cast<const float4*>(wh + obj * 4);
    const float x = flow[(b * 2 + 0) * HWc + idx];
    const float y = flow[(b * 2 + 1) * HWc + idx];

    for (int i = tid; i < CH * Wc; i += 256) s_hm[i] = 0;

    // ---- Phase 2b: param compute + chunk-intersection compaction
    const float w = whv.x + whv.z;
    const float h = whv.y + whv.w;
    if (mk != 0 && h > 0.0f && w > 0.0f && x > 0.0f && y > 0.0f &&
        x < 152.0f && y < 272.0f) {
        // gaussian_radius(ceil(h), ceil(w)) — f32 op order as reference
        const float height = ceilf(h);
        const float width  = ceilf(w);

        const float b1  = height + width;
        const float c1  = width * height * 0.3f / 1.7f;
        const float sq1 = sqrtf(b1 * b1 - 4.0f * c1);
        const float r1  = (b1 + sq1) * 0.5f;

        const float b2  = 2.0f * (height + width);
        const float c2  = 0.3f * width * height;
        const float sq2 = sqrtf(b2 * b2 - 16.0f * c2);
        const float r2  = (b2 + sq2) * 0.5f;

        const float b3  = -1.4f * (height + width);
        const float c3  = -0.3f * width * height;
        const float sq3 = sqrtf(b3 * b3 - 11.2f * c3);
        const float r3  = (b3 + sq3) * 0.5f;

        float radius = fminf(fminf(r1, r2), r3);
        radius = fmaxf(radius, 0.0f);
        if (radius >= 0.0f) {             // NaN guard (can't occur for h,w>0)
            const float rf = floorf(radius);
            int ri = (int)rf;
            if (ri > RMAXc) ri = RMAXc;
            const int yi = (int)floorf(y);
            // window-row intersection with this chunk?
            if (yi + ri >= rowLo && yi - ri <= rowHi - 1) {
                const float sigma = (2.0f * rf + 1.0f) / 6.0f;
                const int pos = atomicAdd(&s_n, 1);
                s_xi[pos] = (int)floorf(x);
                s_yi[pos] = yi;
                s_ri[pos] = ri;
                s_dn[pos] = 2.0f * sigma * sigma;
            }
        }
    }
    __syncthreads();

    // ---- Phase 3: wave-per-listed-object scatter (list is short, ~20)
    const int wave = tid >> 6;
    const int lane = tid & 63;
    const int nobj = s_n;
    for (int o = wave; o < nobj; o += 4) {
        const int   ri = s_ri[o];
        const int   xi = s_xi[o];
        const int   yi = s_yi[o];
        const float dn = s_dn[o];

        int dyLo = -ri, dyHi = ri;
        if (yi + dyLo < rowLo)     dyLo = rowLo - yi;
        if (yi + dyHi > rowHi - 1) dyHi = rowHi - 1 - yi;

        const int dw    = 2 * ri + 1;
        const int ncell = (dyHi - dyLo + 1) * dw;
        for (int c = lane; c < ncell; c += 64) {
            const int dy = dyLo + c / dw;
            const int dx = c % dw - ri;
            const int xx = xi + dx;
            if (xx < 0 || xx >= Wc) continue;
            const float dist2 = (float)(dx * dx + dy * dy);
            const float g = expf(-dist2 / dn);
            if (g < 2e-15f) continue;      // max(0) no-op on zeroed slab
            atomicMax(&s_hm[(yi + dy - rowLo) * Wc + xx], __float_as_int(g));
        }
    }
    __syncthreads();

    // ---- Phase 4: coalesced float4 stream-out
    {
        float4* out4 = reinterpret_cast<float4*>(hm + (size_t)(b * Hc + rowLo) * Wc);
        const float4* l4 = reinterpret_cast<const float4*>(s_hm);
        for (int i = tid; i < CH * W4; i += 256) out4[i] = l4[i];
    }
}

extern "C" void kernel_launch(void* const* d_in, const int* in_sizes, int n_in,
                              void* d_out, int out_size, void* d_ws, size_t ws_size,
                              hipStream_t stream) {
    const float* flow  = (const float*)d_in[0];  // [B,2,H,W] f32
    const float* wh    = (const float*)d_in[1];  // [B,N,4]   f32
    const int*   mask  = (const int*)d_in[2];    // [B,N]     i32
    const int*   index = (const int*)d_in[3];    // [B,N]     i32
    float* hm = (float*)d_out;                   // [B,1,H,W] f32

    // 128 batches x 8 row-chunks = 1024 blocks (4/CU, fully resident).
    fused_gaussian_kernel<<<Bc * SPLIT, 256, 0, stream>>>(flow, wh, mask, index, hm);
}

// Round 5
// 17.930 us; speedup vs baseline: 1.4130x; 1.2621x over previous
//
#include <hip/hip_runtime.h>

// Problem constants (match reference)
constexpr int Bc = 128;
constexpr int Nc = 256;
constexpr int Hc = 272;
constexpr int Wc = 152;
constexpr int RMAXc = 8;
constexpr int HWc = Hc * Wc;

constexpr int SPLIT = 8;          // row chunks per batch image
constexpr int CH    = Hc / SPLIT; // 34 rows per chunk
constexpr int W4    = Wc / 4;     // 38 float4 per row

// One block per (batch, row-chunk); every output byte owned by exactly one
// block (no memset, no global atomics). Loads are PREDICATED and DEFERRED:
//   mask (coalesced) -> index + y-plane gather -> conservative RMAX window
//   test (needs only y) -> wh + x-plane gather + radius math -> precise test
//   -> LDS compaction list. Empty chunks issue zero scattered gathers beyond y.
__global__ __launch_bounds__(256) void fused_gaussian_kernel(
    const float* __restrict__ flow,   // [B,2,H,W]
    const float* __restrict__ wh,     // [B,N,4]
    const int*   __restrict__ mask,   // [B,N]
    const int*   __restrict__ index,  // [B,N]
    float*       __restrict__ hm)     // [B,H,W]
{
    __shared__ int   s_hm[CH * Wc];   // 20672 B
    __shared__ int   s_xi[Nc], s_yi[Nc], s_ri[Nc];
    __shared__ float s_dn[Nc];
    __shared__ int   s_n;

    const int tid   = threadIdx.x;
    const int b     = blockIdx.x >> 3;
    const int chunk = blockIdx.x & 7;
    const int rowLo = chunk * CH;
    const int rowHi = rowLo + CH;

    if (tid == 0) s_n = 0;

    // ---- Predicated param phase ----
    const int obj = b * Nc + tid;
    const int mk  = mask[obj];

    int   idx = 0;
    float y   = -1.0f;
    if (mk != 0) {
        idx = index[obj];
        y   = flow[(b * 2 + 1) * HWc + idx];   // y-plane gather only
    }

    // Zero the slab while the y-gather is in flight (vectorized b128).
    {
        int4* s4 = reinterpret_cast<int4*>(s_hm);
        const int4 z = make_int4(0, 0, 0, 0);
        for (int i = tid; i < CH * W4; i += 256) s4[i] = z;
    }

    if (y > 0.0f && y < 272.0f) {
        const int yi = (int)floorf(y);
        // conservative window test: needs only y (RMAX bound)
        if (yi + RMAXc >= rowLo && yi - RMAXc <= rowHi - 1) {
            const float4 whv = *reinterpret_cast<const float4*>(wh + obj * 4);
            const float x = flow[(b * 2 + 0) * HWc + idx];   // x-plane gather
            const float w = whv.x + whv.z;
            const float h = whv.y + whv.w;
            if (h > 0.0f && w > 0.0f && x > 0.0f && x < 152.0f) {
                // gaussian_radius(ceil(h), ceil(w)) — f32 op order as reference
                const float height = ceilf(h);
                const float width  = ceilf(w);

                const float b1  = height + width;
                const float c1  = width * height * 0.3f / 1.7f;
                const float sq1 = sqrtf(b1 * b1 - 4.0f * c1);
                const float r1  = (b1 + sq1) * 0.5f;

                const float b2  = 2.0f * (height + width);
                const float c2  = 0.3f * width * height;
                const float sq2 = sqrtf(b2 * b2 - 16.0f * c2);
                const float r2  = (b2 + sq2) * 0.5f;

                const float b3  = -1.4f * (height + width);
                const float c3  = -0.3f * width * height;
                const float sq3 = sqrtf(b3 * b3 - 11.2f * c3);
                const float r3  = (b3 + sq3) * 0.5f;

                float radius = fminf(fminf(r1, r2), r3);
                radius = fmaxf(radius, 0.0f);
                if (radius >= 0.0f) {            // NaN guard
                    const float rf = floorf(radius);
                    int ri = (int)rf;
                    if (ri > RMAXc) ri = RMAXc;  // grid bound; sigma uses true rf
                    // precise window-row intersection
                    if (yi + ri >= rowLo && yi - ri <= rowHi - 1) {
                        const float sigma = (2.0f * rf + 1.0f) / 6.0f;
                        const int pos = atomicAdd(&s_n, 1);
                        s_xi[pos] = (int)floorf(x);
                        s_yi[pos] = yi;
                        s_ri[pos] = ri;
                        s_dn[pos] = 2.0f * sigma * sigma;
                    }
                }
            }
        }
    }
    __syncthreads();

    // ---- Scatter: wave-per-listed-object (list ~20-40 entries) ----
    const int wave = tid >> 6;
    const int lane = tid & 63;
    const int nobj = s_n;
    for (int o = wave; o < nobj; o += 4) {
        const int   ri = s_ri[o];
        const int   xi = s_xi[o];
        const int   yi = s_yi[o];
        const float dn = s_dn[o];

        int dyLo = -ri, dyHi = ri;
        if (yi + dyLo < rowLo)     dyLo = rowLo - yi;
        if (yi + dyHi > rowHi - 1) dyHi = rowHi - 1 - yi;

        const int dw    = 2 * ri + 1;
        const int ncell = (dyHi - dyLo + 1) * dw;
        for (int c = lane; c < ncell; c += 64) {
            const int dy = dyLo + c / dw;
            const int dx = c % dw - ri;
            const int xx = xi + dx;
            if (xx < 0 || xx >= Wc) continue;
            const float dist2 = (float)(dx * dx + dy * dy);
            const float g = expf(-dist2 / dn);
            if (g < 2e-15f) continue;      // max(0) no-op on zeroed slab
            // g >= 0 so int-punned max == float max
            atomicMax(&s_hm[(yi + dy - rowLo) * Wc + xx], __float_as_int(g));
        }
    }
    __syncthreads();

    // ---- Coalesced float4 stream-out (each byte written exactly once) ----
    {
        float4* out4 = reinterpret_cast<float4*>(hm + (size_t)(b * Hc + rowLo) * Wc);
        const float4* l4 = reinterpret_cast<const float4*>(s_hm);
        for (int i = tid; i < CH * W4; i += 256) out4[i] = l4[i];
    }
}

extern "C" void kernel_launch(void* const* d_in, const int* in_sizes, int n_in,
                              void* d_out, int out_size, void* d_ws, size_t ws_size,
                              hipStream_t stream) {
    const float* flow  = (const float*)d_in[0];  // [B,2,H,W] f32
    const float* wh    = (const float*)d_in[1];  // [B,N,4]   f32
    const int*   mask  = (const int*)d_in[2];    // [B,N]     i32
    const int*   index = (const int*)d_in[3];    // [B,N]     i32
    float* hm = (float*)d_out;                   // [B,1,H,W] f32

    // 128 batches x 8 row-chunks = 1024 blocks (4/CU, fully resident).
    fused_gaussian_kernel<<<Bc * SPLIT, 256, 0, stream>>>(flow, wh, mask, index, hm);
}